// Round 3
// baseline (5215.412 us; speedup 1.0000x reference)
//
#include <hip/hip_runtime.h>
#include <hip/hip_bf16.h>
#include <math.h>

typedef __hip_bfloat16 bf16;

#define B_    4
#define C_    180
#define ROWS_ 65536   // B*H*W
#define NH_   6
#define HD_   30
#define NT_   256     // tokens per window
#define CC_   60      // conv mid channels
#define HID_  720
#define CH_   8       // row chunks
#define CROWS_ 8192   // rows per chunk
#define CWIN_  32     // windows per chunk
#define ATT_SCALE 0.18257418583505536f  // 30^-0.5

__device__ __forceinline__ float b2f(bf16 v){ return __bfloat162float(v); }
__device__ __forceinline__ bf16  f2b(float v){ return __float2bfloat16(v); }
__device__ __forceinline__ float ldf(const bf16* p){ return __bfloat162float(*p); }
__device__ __forceinline__ float ldf(const float* p){ return *p; }
__device__ __forceinline__ float gelu_f(float v){
    return 0.5f * v * (1.0f + erff(v * 0.70710678118654752440f));
}

// window-ordered row r -> natural row
__device__ __forceinline__ int inv_win(int r){
    int b = r >> 14, w6 = (r >> 8) & 63, t = r & 255;
    int py = ((w6 >> 3) << 4) + (t >> 4);
    int px = ((w6 & 7) << 4) + (t & 15);
    return (b << 14) + (py << 7) + px;
}

// ---------------- LayerNorm: one wave per row of 180 ----------------
template<typename TIN>
__global__ __launch_bounds__(256) void ln_kernel(const TIN* __restrict__ xin,
        const float* __restrict__ gw, const float* __restrict__ gb,
        bf16* __restrict__ xn)
{
    int row  = blockIdx.x * 4 + (threadIdx.x >> 6);
    int lane = threadIdx.x & 63;
    const TIN* xp = xin + (size_t)row * C_;
    float v0 = ldf(xp + lane);
    float v1 = ldf(xp + lane + 64);
    float v2 = (lane < 52) ? ldf(xp + lane + 128) : 0.f;
    float s  = v0 + v1 + v2;
    float sq = v0*v0 + v1*v1 + v2*v2;
    for (int off = 32; off > 0; off >>= 1){
        s  += __shfl_xor(s,  off);
        sq += __shfl_xor(sq, off);
    }
    float mu  = s * (1.f / 180.f);
    float inv = rsqrtf(sq * (1.f / 180.f) - mu * mu + 1e-5f);
    size_t ro = (size_t)row * C_;
    #pragma unroll
    for (int e = 0; e < 3; e++){
        int c = lane + e * 64;
        if (c < C_){
            float v = (e == 0) ? v0 : (e == 1 ? v1 : v2);
            xn[ro + c] = f2b((v - mu) * inv * gw[c] + gb[c]);
        }
    }
}

// ---------------- conv1 3x3 C->CC + GELU ----------------
__global__ __launch_bounds__(256) void conv1_kernel(const bf16* __restrict__ xn,
        const float* __restrict__ w, const float* __restrict__ bias, bf16* __restrict__ y1)
{
    int idx = blockIdx.x * 256 + threadIdx.x;
    int co  = idx % CC_;
    int pix = idx / CC_;
    int px = pix & 127, py = (pix >> 7) & 127, b = pix >> 14;
    float acc = bias[co];
    for (int kh = 0; kh < 3; kh++){
        int y = py + kh - 1;
        if ((unsigned)y >= 128u) continue;
        for (int kw = 0; kw < 3; kw++){
            int x = px + kw - 1;
            if ((unsigned)x >= 128u) continue;
            const bf16* ip = xn + ((size_t)(b << 14) + (y << 7) + x) * C_;
            const float* wp = w + (size_t)((kh * 3 + kw) * C_) * CC_ + co;
            #pragma unroll 4
            for (int ci = 0; ci < C_; ci++)
                acc += b2f(ip[ci]) * wp[ci * CC_];
        }
    }
    y1[idx] = f2b(gelu_f(acc));
}

// ---------------- conv2 3x3 CC->C ----------------
__global__ __launch_bounds__(256) void conv2_kernel(const bf16* __restrict__ y1,
        const float* __restrict__ w, const float* __restrict__ bias, bf16* __restrict__ y2)
{
    int idx = blockIdx.x * 256 + threadIdx.x;
    int co  = idx % C_;
    int pix = idx / C_;
    int px = pix & 127, py = (pix >> 7) & 127, b = pix >> 14;
    float acc = bias[co];
    for (int kh = 0; kh < 3; kh++){
        int y = py + kh - 1;
        if ((unsigned)y >= 128u) continue;
        for (int kw = 0; kw < 3; kw++){
            int x = px + kw - 1;
            if ((unsigned)x >= 128u) continue;
            const bf16* ip = y1 + ((size_t)(b << 14) + (y << 7) + x) * CC_;
            const float* wp = w + (size_t)((kh * 3 + kw) * CC_) * C_ + co;
            #pragma unroll 4
            for (int ci = 0; ci < CC_; ci++)
                acc += b2f(ip[ci]) * wp[ci * C_];
        }
    }
    y2[idx] = f2b(acc);
}

// ---------------- adaptive avg pool partials ----------------
__global__ __launch_bounds__(192) void pool_kernel(const bf16* __restrict__ y2,
                                                   float* __restrict__ pooled)
{
    int b = blockIdx.x >> 6;
    int chunk = blockIdx.x & 63;
    int c = threadIdx.x;
    if (c >= C_) return;
    const bf16* p = y2 + ((size_t)(b << 14) + (chunk << 8)) * C_ + c;
    float s = 0.f;
    for (int i = 0; i < 256; i++) s += b2f(p[(size_t)i * C_]);
    atomicAdd(&pooled[b * C_ + c], s);
}

// ---------------- channel attention tiny MLP ----------------
__global__ __launch_bounds__(192) void ca_kernel(const float* __restrict__ pooled,
        const float* __restrict__ w1, const float* __restrict__ b1,
        const float* __restrict__ w2, const float* __restrict__ b2v,
        float* __restrict__ aout)
{
    __shared__ float t[NH_];
    int b = blockIdx.x, tid = threadIdx.x;
    if (tid < 6){
        float s = b1[tid];
        for (int c = 0; c < C_; c++)
            s += pooled[b * C_ + c] * (1.f / 16384.f) * w1[c * 6 + tid];
        t[tid] = fmaxf(s, 0.f);
    }
    __syncthreads();
    if (tid < C_){
        float s = b2v[tid];
        #pragma unroll
        for (int j = 0; j < 6; j++) s += t[j] * w2[j * C_ + tid];
        aout[b * C_ + tid] = 1.f / (1.f + __expf(-s));
    }
}

// ---------------- relative position bias table (bf16) ----------------
__global__ __launch_bounds__(256) void rpb_kernel(const float* __restrict__ rpb,
        const int* __restrict__ rpi, bf16* __restrict__ biasT)
{
    int idx = blockIdx.x * 256 + threadIdx.x;     // h*65536 + i*256 + j
    int h = idx >> 16, ij = idx & 65535;
    biasT[idx] = f2b(rpb[rpi[ij] * 6 + h]);
}

// ---------------- generic GEMM, 64x64 tile, fp32 LDS, swizzled A ----------------
// A is bf16; Bw/bias are fp32 weights.
// EPI 0: bias -> bf16 out (local rows)   1: bias+GELU -> bf16 out (local rows)
// EPI 2: bias + bf16 residual -> fp32 out (local rows, final output)
// EPI 3: bias + scatter-residual in place over bf16 resbuf (window->natural)
__device__ __forceinline__ int asw(int k, int col){ return col ^ (((k >> 1) & 15) << 2); }

template<int EPI, bool GATHER, typename OutT>
__global__ __launch_bounds__(256) void gemm_kernel(const bf16* __restrict__ A,
        const float* __restrict__ Bw, const float* __restrict__ bias,
        OutT* out, int N, int K, int row0,
        const float* xres, const bf16* resb, const float* __restrict__ aab)
{
    __shared__ float As[32][64];
    __shared__ float Bs[32][64];
    int tid = threadIdx.x;
    int gm0 = blockIdx.x * 64;
    int gn0 = blockIdx.y * 64;
    float acc[4][4] = {};
    int ty = tid >> 4, tx = tid & 15;
    int akk = (tid & 15) * 2, amb = tid >> 4;
    int bnn = (tid & 31) * 2, bkb = tid >> 5;
    int nkt = (K + 31) / 32;
    for (int kt = 0; kt < nkt; kt++){
        int k0 = kt * 32;
        #pragma unroll
        for (int pp = 0; pp < 4; pp++){
            int m = amb + pp * 16;
            int gk = k0 + akk;
            int arow = gm0 + m;
            if (GATHER) arow = inv_win(row0 + arow);
            const bf16* ap = A + (size_t)arow * K + gk;
            float a0 = (gk     < K) ? b2f(ap[0]) : 0.f;
            float a1 = (gk + 1 < K) ? b2f(ap[1]) : 0.f;
            int sc = asw(akk, m);
            As[akk][sc] = a0;
            As[akk + 1][sc] = a1;
        }
        #pragma unroll
        for (int pp = 0; pp < 4; pp++){
            int k = bkb + pp * 8;
            int gk = k0 + k, gn = gn0 + bnn;
            float b0 = 0.f, b1 = 0.f;
            if (gk < K){
                const float* bp = Bw + (size_t)gk * N + gn;
                if (gn     < N) b0 = bp[0];
                if (gn + 1 < N) b1 = bp[1];
            }
            Bs[k][bnn] = b0;
            Bs[k][bnn + 1] = b1;
        }
        __syncthreads();
        #pragma unroll
        for (int k = 0; k < 32; k++){
            float4 av = *(const float4*)&As[k][asw(k, ty * 4)];
            float4 bv = *(const float4*)&Bs[k][tx * 4];
            float am[4] = {av.x, av.y, av.z, av.w};
            float bn[4] = {bv.x, bv.y, bv.z, bv.w};
            #pragma unroll
            for (int i = 0; i < 4; i++)
                #pragma unroll
                for (int j = 0; j < 4; j++)
                    acc[i][j] += am[i] * bn[j];
        }
        __syncthreads();
    }
    float bj[4];
    #pragma unroll
    for (int j = 0; j < 4; j++){
        int gc = gn0 + tx * 4 + j;
        bj[j] = (gc < N) ? bias[gc] : 0.f;
    }
    #pragma unroll
    for (int i = 0; i < 4; i++){
        int gr = gm0 + ty * 4 + i;
        #pragma unroll
        for (int j = 0; j < 4; j++){
            int gc = gn0 + tx * 4 + j;
            if (gc >= N) continue;
            float v = acc[i][j] + bj[j];
            if (EPI == 1) v = gelu_f(v);
            if (EPI == 0 || EPI == 1){
                out[(size_t)gr * N + gc] = (OutT)f2b(v);
            } else if (EPI == 2){
                size_t oi = (size_t)gr * N + gc;
                ((float*)out)[oi] = v + b2f(resb[oi]);
            } else {  // EPI == 3, in-place over bf16 resbuf
                int nr = inv_win(row0 + gr);
                size_t oi = (size_t)nr * C_ + gc;
                bf16* ob = (bf16*)out;
                v += xres[oi] + b2f(ob[oi]) * aab[(nr >> 14) * C_ + gc] * 0.01f;
                ob[oi] = f2b(v);
            }
        }
    }
}

// ---------------- windowed attention: one block per (window, head), chunk-local ----
__global__ __launch_bounds__(128) void attn_kernel(const bf16* __restrict__ qkv,
        const bf16* __restrict__ biasT, bf16* __restrict__ attn_o)
{
    __shared__ float Ks[NT_][HD_];
    __shared__ float Vs[NT_][HD_];
    int win = blockIdx.x / NH_;   // chunk-local window
    int h   = blockIdx.x % NH_;
    int t   = threadIdx.x;
    size_t base = (size_t)win * NT_ * 540;
    for (int r = t; r < NT_; r += 128){
        const bf16* kp = qkv + base + (size_t)r * 540 + C_ + h * HD_;
        const bf16* vp = kp + C_;
        #pragma unroll
        for (int d = 0; d < HD_; d++){ Ks[r][d] = b2f(kp[d]); Vs[r][d] = b2f(vp[d]); }
    }
    float q0[HD_], q1[HD_];
    {
        const bf16* qp0 = qkv + base + (size_t)t * 540 + h * HD_;
        const bf16* qp1 = qkv + base + (size_t)(t + 128) * 540 + h * HD_;
        #pragma unroll
        for (int d = 0; d < HD_; d++){
            q0[d] = b2f(qp0[d]) * ATT_SCALE;
            q1[d] = b2f(qp1[d]) * ATT_SCALE;
        }
    }
    __syncthreads();
    float acc0[HD_] = {}, acc1[HD_] = {};
    float l0 = 0.f, l1 = 0.f;
    const bf16* bp0 = biasT + (size_t)h * 65536 + (size_t)t * 256;
    const bf16* bp1 = bp0 + 128 * 256;
    for (int j = 0; j < NT_; j++){
        float s0 = b2f(bp0[j]), s1 = b2f(bp1[j]);
        #pragma unroll
        for (int d = 0; d < HD_; d++){
            float kv = Ks[j][d];
            s0 += q0[d] * kv;
            s1 += q1[d] * kv;
        }
        float p0 = __expf(s0), p1 = __expf(s1);
        l0 += p0; l1 += p1;
        #pragma unroll
        for (int d = 0; d < HD_; d++){
            float vv = Vs[j][d];
            acc0[d] += p0 * vv;
            acc1[d] += p1 * vv;
        }
    }
    float r0 = 1.f / l0, r1 = 1.f / l1;
    bf16* o0 = attn_o + ((size_t)win * NT_ + t) * C_ + h * HD_;
    bf16* o1 = o0 + (size_t)128 * C_;
    #pragma unroll
    for (int d = 0; d < HD_; d++){
        o0[d] = f2b(acc0[d] * r0);
        o1[d] = f2b(acc1[d] * r1);
    }
}

extern "C" void kernel_launch(void* const* d_in, const int* in_sizes, int n_in,
                              void* d_out, int out_size, void* d_ws, size_t ws_size,
                              hipStream_t stream)
{
    const float* x      = (const float*)d_in[0];
    const int*   rpi    = (const int*)  d_in[1];
    const float* n1g    = (const float*)d_in[6];
    const float* n1b    = (const float*)d_in[7];
    const float* qkv_w  = (const float*)d_in[8];
    const float* qkv_b  = (const float*)d_in[9];
    const float* rpb    = (const float*)d_in[10];
    const float* proj_w = (const float*)d_in[11];
    const float* proj_b = (const float*)d_in[12];
    const float* c1w    = (const float*)d_in[13];
    const float* c1b    = (const float*)d_in[14];
    const float* c2w    = (const float*)d_in[15];
    const float* c2b    = (const float*)d_in[16];
    const float* ca1w   = (const float*)d_in[17];
    const float* ca1b   = (const float*)d_in[18];
    const float* ca2w   = (const float*)d_in[19];
    const float* ca2b   = (const float*)d_in[20];
    const float* n2g    = (const float*)d_in[21];
    const float* n2b    = (const float*)d_in[22];
    const float* fc1w   = (const float*)d_in[23];
    const float* fc1b   = (const float*)d_in[24];
    const float* fc2w   = (const float*)d_in[25];
    const float* fc2b   = (const float*)d_in[26];

    // ---- workspace layout: total 59,774,592 B (~57 MiB), bf16 intermediates ----
    char* ws = (char*)d_ws;
    bf16*  slab   = (bf16*)(ws);                        // 11,796,480 B chunk slab
    bf16*  qkvb   = slab;                               // 8,847,360 B (chunk)
    bf16*  attn_o = (bf16*)(ws + 8847360);              // 2,949,120 B (chunk)
    bf16*  hbuf   = slab;                               // 11,796,480 B (chunk)
    bf16*  y1     = slab;                               // 7,864,320 B (pre-qkv)
    bf16*  xn     = (bf16*)(ws + 11796480);             // 23,592,960 B  xn / xn2
    bf16*  resbuf = (bf16*)(ws + 35389440);             // 23,592,960 B  y2 / xr
    bf16*  biasT  = (bf16*)(ws + 58982400);             // 786,432 B
    float* pooled = (float*)(ws + 59768832);            // 2,880 B
    float* aab    = (float*)(ws + 59771712);            // 2,880 B

    hipMemsetAsync(pooled, 0, B_ * C_ * sizeof(float), stream);
    ln_kernel<float><<<16384, 256, 0, stream>>>(x, n1g, n1b, xn);
    conv1_kernel<<<15360, 256, 0, stream>>>(xn, c1w, c1b, y1);
    conv2_kernel<<<46080, 256, 0, stream>>>(y1, c2w, c2b, resbuf);
    pool_kernel<<<256, 192, 0, stream>>>(resbuf, pooled);
    ca_kernel<<<4, 192, 0, stream>>>(pooled, ca1w, ca1b, ca2w, ca2b, aab);
    rpb_kernel<<<1536, 256, 0, stream>>>(rpb, rpi, biasT);

    for (int ch = 0; ch < CH_; ch++){
        int row0 = ch * CROWS_;
        gemm_kernel<0, true, bf16><<<dim3(128, 9), 256, 0, stream>>>(
            xn, qkv_w, qkv_b, qkvb, 540, 180, row0, nullptr, nullptr, nullptr);
        attn_kernel<<<CWIN_ * NH_, 128, 0, stream>>>(qkvb, biasT, attn_o);
        gemm_kernel<3, false, bf16><<<dim3(128, 3), 256, 0, stream>>>(
            attn_o, proj_w, proj_b, resbuf, 180, 180, row0, x, nullptr, aab);
    }

    ln_kernel<bf16><<<16384, 256, 0, stream>>>(resbuf, n2g, n2b, xn);   // xn2 reuses xn

    for (int ch = 0; ch < CH_; ch++){
        size_t off = (size_t)ch * CROWS_ * C_;
        gemm_kernel<1, false, bf16><<<dim3(128, 12), 256, 0, stream>>>(
            xn + off, fc1w, fc1b, hbuf, 720, 180, 0, nullptr, nullptr, nullptr);
        gemm_kernel<2, false, float><<<dim3(128, 3), 256, 0, stream>>>(
            hbuf, fc2w, fc2b, (float*)d_out + off, 180, 720, 0, nullptr, resbuf + off, nullptr);
    }
}

// Round 4
// 1236.007 us; speedup vs baseline: 4.2196x; 4.2196x over previous
//
#include <hip/hip_runtime.h>
#include <hip/hip_bf16.h>
#include <math.h>

typedef __hip_bfloat16 bf16;

#define B_    4
#define C_    180
#define ROWS_ 65536   // B*H*W
#define NH_   6
#define HD_   30
#define NT_   256     // tokens per window
#define CC_   60      // conv mid channels
#define HID_  720
#define CH_   4       // row chunks
#define CROWS_ 16384  // rows per chunk
#define CWIN_  64     // windows per chunk
#define ATT_SCALE 0.18257418583505536f  // 30^-0.5

typedef short  short4v __attribute__((ext_vector_type(4)));
typedef short  short8v __attribute__((ext_vector_type(8)));
typedef __bf16 bf16x8  __attribute__((ext_vector_type(8)));
typedef float  f32x4   __attribute__((ext_vector_type(4)));

__device__ __forceinline__ float b2f(bf16 v){ return __bfloat162float(v); }
__device__ __forceinline__ bf16  f2b(float v){ return __float2bfloat16(v); }
__device__ __forceinline__ float ldf(const bf16* p){ return __bfloat162float(*p); }
__device__ __forceinline__ float ldf(const float* p){ return *p; }
__device__ __forceinline__ float gelu_f(float v){
    return 0.5f * v * (1.0f + erff(v * 0.70710678118654752440f));
}
__device__ __forceinline__ f32x4 mfma16(short8v a, short8v b, f32x4 c){
    return __builtin_amdgcn_mfma_f32_16x16x32_bf16(
        __builtin_bit_cast(bf16x8, a), __builtin_bit_cast(bf16x8, b), c, 0, 0, 0);
}

// window-ordered row r -> natural row
__device__ __forceinline__ int inv_win(int r){
    int b = r >> 14, w6 = (r >> 8) & 63, t = r & 255;
    int py = ((w6 >> 3) << 4) + (t >> 4);
    int px = ((w6 & 7) << 4) + (t & 15);
    return (b << 14) + (py << 7) + px;
}

// ---------------- LayerNorm: one wave per row of 180 ----------------
template<typename TIN>
__global__ __launch_bounds__(256) void ln_kernel(const TIN* __restrict__ xin,
        const float* __restrict__ gw, const float* __restrict__ gb,
        bf16* __restrict__ xn)
{
    int row  = blockIdx.x * 4 + (threadIdx.x >> 6);
    int lane = threadIdx.x & 63;
    const TIN* xp = xin + (size_t)row * C_;
    float v0 = ldf(xp + lane);
    float v1 = ldf(xp + lane + 64);
    float v2 = (lane < 52) ? ldf(xp + lane + 128) : 0.f;
    float s  = v0 + v1 + v2;
    float sq = v0*v0 + v1*v1 + v2*v2;
    for (int off = 32; off > 0; off >>= 1){
        s  += __shfl_xor(s,  off);
        sq += __shfl_xor(sq, off);
    }
    float mu  = s * (1.f / 180.f);
    float inv = rsqrtf(sq * (1.f / 180.f) - mu * mu + 1e-5f);
    size_t ro = (size_t)row * C_;
    #pragma unroll
    for (int e = 0; e < 3; e++){
        int c = lane + e * 64;
        if (c < C_){
            float v = (e == 0) ? v0 : (e == 1 ? v1 : v2);
            xn[ro + c] = f2b((v - mu) * inv * gw[c] + gb[c]);
        }
    }
}

// ---------------- weight transpose: W[K][N] -> BT[NP][KP] bf16, zero-padded ----
__global__ __launch_bounds__(256) void twt_kernel(const float* __restrict__ w,
        bf16* __restrict__ bt, int K, int N, int KP, int NP)
{
    int idx = blockIdx.x * 256 + threadIdx.x;
    if (idx >= NP * KP) return;
    int n = idx / KP, k = idx % KP;
    float v = (n < N && k < K) ? w[(size_t)k * N + n] : 0.f;
    bt[idx] = f2b(v);
}
// conv weight: w[((seg*CIN+ci))*N + n] -> BT[NP][9*SEGP]
__global__ __launch_bounds__(256) void twc_kernel(const float* __restrict__ w,
        bf16* __restrict__ bt, int CIN, int N, int SEGP, int NP)
{
    int KP = 9 * SEGP;
    int idx = blockIdx.x * 256 + threadIdx.x;
    if (idx >= NP * KP) return;
    int n = idx / KP, kk = idx % KP;
    int seg = kk / SEGP, ci = kk - seg * SEGP;
    float v = (n < N && ci < CIN) ? w[((size_t)seg * CIN + ci) * N + n] : 0.f;
    bt[idx] = f2b(v);
}

// ---------------- adaptive avg pool partials ----------------
__global__ __launch_bounds__(192) void pool_kernel(const bf16* __restrict__ y2,
                                                   float* __restrict__ pooled)
{
    int b = blockIdx.x >> 6;
    int chunk = blockIdx.x & 63;
    int c = threadIdx.x;
    if (c >= C_) return;
    const bf16* p = y2 + ((size_t)(b << 14) + (chunk << 8)) * C_ + c;
    float s = 0.f;
    for (int i = 0; i < 256; i++) s += b2f(p[(size_t)i * C_]);
    atomicAdd(&pooled[b * C_ + c], s);
}

// ---------------- channel attention tiny MLP ----------------
__global__ __launch_bounds__(192) void ca_kernel(const float* __restrict__ pooled,
        const float* __restrict__ w1, const float* __restrict__ b1,
        const float* __restrict__ w2, const float* __restrict__ b2v,
        float* __restrict__ aout)
{
    __shared__ float t[NH_];
    int b = blockIdx.x, tid = threadIdx.x;
    if (tid < 6){
        float s = b1[tid];
        for (int c = 0; c < C_; c++)
            s += pooled[b * C_ + c] * (1.f / 16384.f) * w1[c * 6 + tid];
        t[tid] = fmaxf(s, 0.f);
    }
    __syncthreads();
    if (tid < C_){
        float s = b2v[tid];
        #pragma unroll
        for (int j = 0; j < 6; j++) s += t[j] * w2[j * C_ + tid];
        aout[b * C_ + tid] = 1.f / (1.f + __expf(-s));
    }
}

// ---------------- relative position bias table (bf16) ----------------
__global__ __launch_bounds__(256) void rpb_kernel(const float* __restrict__ rpb,
        const int* __restrict__ rpi, bf16* __restrict__ biasT)
{
    int idx = blockIdx.x * 256 + threadIdx.x;     // h*65536 + i*256 + j
    int h = idx >> 16, ij = idx & 65535;
    biasT[idx] = f2b(rpb[rpi[ij] * 6 + h]);
}

// ================= unified MFMA GEMM =================
// Tile 256(M) x 64(N), BK=32, 4 waves; wave computes 64x64 via 4x4 mfma_f32_16x16x32_bf16.
// MODE 0: A[arow*ldA + k]            1: arow = inv_win(row0+row), ldA
//      2: conv gather (SEGP,CSTR): k -> (seg=kh*3+kw, ci), pixel shifted, border->0
// EPI  0: bias -> bf16 out           1: bias+GELU -> bf16 out
//      2: bias + bf16 resb -> fp32 out
//      3: bias + scatter-residual in place over bf16 resbuf (window->natural)
template<int EPI, int MODE, int SEGP, int CSTR>
__global__ __launch_bounds__(256) void mgemm_kernel(const bf16* __restrict__ A,
        const bf16* __restrict__ BT, const float* __restrict__ bias,
        void* outp, int N, int KP, int row0, int ldA,
        const float* __restrict__ xres, const bf16* __restrict__ resb,
        const float* __restrict__ aab)
{
    __shared__ short As[256 * 32];
    __shared__ short Bs[64 * 32];
    int tid = threadIdx.x;
    int gm0 = blockIdx.x * 256;
    int n0  = blockIdx.y * 64;
    f32x4 acc[4][4];
    #pragma unroll
    for (int i = 0; i < 4; i++)
        #pragma unroll
        for (int j = 0; j < 4; j++)
            acc[i][j] = (f32x4)0.f;

    int r_ = tid >> 2;          // 0..63
    int q_ = tid & 3;           // logical 8-elem k-chunk
    int lane = tid & 63, wv = tid >> 6;
    int quad = lane >> 4, l15 = lane & 15;
    int nch = KP >> 5;

    for (int kc = 0; kc < nch; kc++){
        int k0 = kc * 32;
        int gk = k0 + q_ * 8;
        // ---- stage A (256 rows x 32 k) ----
        #pragma unroll
        for (int s = 0; s < 4; s++){
            int r = r_ + s * 64;
            short8v val;
            if (MODE == 2){
                int mg = gm0 + r;
                int bb = mg >> 14, p = mg & 16383;
                int py = p >> 7, px = p & 127;
                int seg = k0 / SEGP;
                int kh = seg / 3, kw = seg - kh * 3;
                int ci = gk - seg * SEGP;
                int y = py + kh - 1, x = px + kw - 1;
                if ((unsigned)y < 128u && (unsigned)x < 128u){
                    const bf16* ap = A + ((size_t)(bb << 14) + (y << 7) + x) * CSTR + ci;
                    short4v lo = *(const short4v*)ap;
                    short4v hi = *(const short4v*)(ap + 4);
                    val = short8v{lo[0],lo[1],lo[2],lo[3],hi[0],hi[1],hi[2],hi[3]};
                } else {
                    val = short8v{0,0,0,0,0,0,0,0};
                }
            } else {
                int arow = gm0 + r;
                if (MODE == 1) arow = inv_win(row0 + arow);
                const bf16* ap = A + (size_t)arow * ldA + gk;
                short4v lo = *(const short4v*)ap;
                short4v hi = *(const short4v*)(ap + 4);
                val = short8v{lo[0],lo[1],lo[2],lo[3],hi[0],hi[1],hi[2],hi[3]};
            }
            int pp = q_ ^ ((r >> 1) & 3);
            *(short8v*)&As[r * 32 + pp * 8] = val;
        }
        // ---- stage B^T (64 n x 32 k) ----
        {
            int n = tid >> 2;
            const bf16* bp = BT + (size_t)(n0 + n) * KP + gk;
            short4v lo = *(const short4v*)bp;
            short4v hi = *(const short4v*)(bp + 4);
            int pp = q_ ^ ((n >> 1) & 3);
            *(short8v*)&Bs[n * 32 + pp * 8] =
                short8v{lo[0],lo[1],lo[2],lo[3],hi[0],hi[1],hi[2],hi[3]};
        }
        __syncthreads();
        // ---- fragments + MFMA ----
        short8v af[4], bfr[4];
        #pragma unroll
        for (int i = 0; i < 4; i++){
            int r = wv * 64 + i * 16 + l15;
            int pp = quad ^ ((r >> 1) & 3);
            af[i] = *(const short8v*)&As[r * 32 + pp * 8];
        }
        #pragma unroll
        for (int j = 0; j < 4; j++){
            int n = j * 16 + l15;
            int pp = quad ^ ((n >> 1) & 3);
            bfr[j] = *(const short8v*)&Bs[n * 32 + pp * 8];
        }
        #pragma unroll
        for (int i = 0; i < 4; i++)
            #pragma unroll
            for (int j = 0; j < 4; j++)
                acc[i][j] = mfma16(af[i], bfr[j], acc[i][j]);
        __syncthreads();
    }

    // ---- epilogue: C/D layout col=lane&15, row=quad*4+reg ----
    #pragma unroll
    for (int i = 0; i < 4; i++){
        #pragma unroll
        for (int reg = 0; reg < 4; reg++){
            int gr = gm0 + wv * 64 + i * 16 + quad * 4 + reg;
            #pragma unroll
            for (int j = 0; j < 4; j++){
                int gc = n0 + j * 16 + l15;
                if (gc >= N) continue;
                float v = acc[i][j][reg] + bias[gc];
                if (EPI == 1) v = gelu_f(v);
                if (EPI == 0 || EPI == 1){
                    ((bf16*)outp)[(size_t)gr * N + gc] = f2b(v);
                } else if (EPI == 2){
                    size_t oi = (size_t)gr * N + gc;
                    ((float*)outp)[oi] = v + b2f(resb[oi]);
                } else {
                    int nr = inv_win(row0 + gr);
                    size_t oi = (size_t)nr * C_ + gc;
                    bf16* ob = (bf16*)outp;
                    v += xres[oi] + b2f(ob[oi]) * aab[(nr >> 14) * C_ + gc] * 0.01f;
                    ob[oi] = f2b(v);
                }
            }
        }
    }
}

// ---------------- windowed attention: one block per (window, head), chunk-local ----
__global__ __launch_bounds__(128) void attn_kernel(const bf16* __restrict__ qkv,
        const bf16* __restrict__ biasT, bf16* __restrict__ attn_o)
{
    __shared__ float Ks[NT_][HD_];
    __shared__ float Vs[NT_][HD_];
    int win = blockIdx.x / NH_;   // chunk-local window
    int h   = blockIdx.x % NH_;
    int t   = threadIdx.x;
    size_t base = (size_t)win * NT_ * 540;
    for (int r = t; r < NT_; r += 128){
        const bf16* kp = qkv + base + (size_t)r * 540 + C_ + h * HD_;
        const bf16* vp = kp + C_;
        #pragma unroll
        for (int d = 0; d < HD_; d++){ Ks[r][d] = b2f(kp[d]); Vs[r][d] = b2f(vp[d]); }
    }
    float q0[HD_], q1[HD_];
    {
        const bf16* qp0 = qkv + base + (size_t)t * 540 + h * HD_;
        const bf16* qp1 = qkv + base + (size_t)(t + 128) * 540 + h * HD_;
        #pragma unroll
        for (int d = 0; d < HD_; d++){
            q0[d] = b2f(qp0[d]) * ATT_SCALE;
            q1[d] = b2f(qp1[d]) * ATT_SCALE;
        }
    }
    __syncthreads();
    float acc0[HD_] = {}, acc1[HD_] = {};
    float l0 = 0.f, l1 = 0.f;
    const bf16* bp0 = biasT + (size_t)h * 65536 + (size_t)t * 256;
    const bf16* bp1 = bp0 + 128 * 256;
    for (int j = 0; j < NT_; j++){
        float s0 = b2f(bp0[j]), s1 = b2f(bp1[j]);
        #pragma unroll
        for (int d = 0; d < HD_; d++){
            float kv = Ks[j][d];
            s0 += q0[d] * kv;
            s1 += q1[d] * kv;
        }
        float p0 = __expf(s0), p1 = __expf(s1);
        l0 += p0; l1 += p1;
        #pragma unroll
        for (int d = 0; d < HD_; d++){
            float vv = Vs[j][d];
            acc0[d] += p0 * vv;
            acc1[d] += p1 * vv;
        }
    }
    float r0 = 1.f / l0, r1 = 1.f / l1;
    bf16* o0 = attn_o + ((size_t)win * NT_ + t) * C_ + h * HD_;
    bf16* o1 = o0 + (size_t)128 * C_;
    #pragma unroll
    for (int d = 0; d < HD_; d++){
        o0[d] = f2b(acc0[d] * r0);
        o1[d] = f2b(acc1[d] * r1);
    }
}

extern "C" void kernel_launch(void* const* d_in, const int* in_sizes, int n_in,
                              void* d_out, int out_size, void* d_ws, size_t ws_size,
                              hipStream_t stream)
{
    const float* x      = (const float*)d_in[0];
    const int*   rpi    = (const int*)  d_in[1];
    const float* n1g    = (const float*)d_in[6];
    const float* n1b    = (const float*)d_in[7];
    const float* qkv_w  = (const float*)d_in[8];
    const float* qkv_b  = (const float*)d_in[9];
    const float* rpb    = (const float*)d_in[10];
    const float* proj_w = (const float*)d_in[11];
    const float* proj_b = (const float*)d_in[12];
    const float* c1w    = (const float*)d_in[13];
    const float* c1b    = (const float*)d_in[14];
    const float* c2w    = (const float*)d_in[15];
    const float* c2b    = (const float*)d_in[16];
    const float* ca1w   = (const float*)d_in[17];
    const float* ca1b   = (const float*)d_in[18];
    const float* ca2w   = (const float*)d_in[19];
    const float* ca2b   = (const float*)d_in[20];
    const float* n2g    = (const float*)d_in[21];
    const float* n2b    = (const float*)d_in[22];
    const float* fc1w   = (const float*)d_in[23];
    const float* fc1b   = (const float*)d_in[24];
    const float* fc2w   = (const float*)d_in[25];
    const float* fc2b   = (const float*)d_in[26];

    // ---- workspace layout (~69.5 MB) ----
    char* ws = (char*)d_ws;
    bf16*  slab   = (bf16*)(ws);                 // 23,592,960 B: y1 / (qkvb+attn_o) / hbuf
    bf16*  y1     = slab;                        // 65536*60*2 = 7,864,320
    bf16*  qkvb   = slab;                        // 16384*540*2 = 17,694,720
    bf16*  attn_o = (bf16*)(ws + 17694720);      // 16384*180*2 = 5,898,240
    bf16*  hbuf   = slab;                        // 16384*720*2 = 23,592,960
    bf16*  xn     = (bf16*)(ws + 23592960);      // 23,592,960  xn / xn2
    bf16*  resbuf = (bf16*)(ws + 47185920);      // 23,592,960  y2 / x-residual
    bf16*  biasT  = (bf16*)(ws + 70778880);      // 786,432
    bf16*  qkvT   = (bf16*)(ws + 71565312);      // 576*192*2 = 221,184
    bf16*  projT  = (bf16*)(ws + 71786496);      // 192*192*2 = 73,728
    bf16*  fc1T   = (bf16*)(ws + 71860224);      // 768*192*2 = 294,912
    bf16*  fc2T   = (bf16*)(ws + 72155136);      // 192*736*2 = 282,624
    bf16*  c1T    = (bf16*)(ws + 72437760);      // 64*1728*2 = 221,184
    bf16*  c2T    = (bf16*)(ws + 72658944);      // 192*576*2 = 221,184
    float* pooled = (float*)(ws + 72880128);     // 2,880
    float* aab    = (float*)(ws + 72883008);     // 2,880

    hipMemsetAsync(pooled, 0, B_ * C_ * sizeof(float), stream);
    rpb_kernel<<<1536, 256, 0, stream>>>(rpb, rpi, biasT);
    twt_kernel<<<(576*192+255)/256, 256, 0, stream>>>(qkv_w, qkvT, 180, 540, 192, 576);
    twt_kernel<<<(192*192+255)/256, 256, 0, stream>>>(proj_w, projT, 180, 180, 192, 192);
    twt_kernel<<<(768*192+255)/256, 256, 0, stream>>>(fc1w, fc1T, 180, 720, 192, 768);
    twt_kernel<<<(192*736+255)/256, 256, 0, stream>>>(fc2w, fc2T, 720, 180, 736, 192);
    twc_kernel<<<(64*1728+255)/256, 256, 0, stream>>>(c1w, c1T, 180, 60, 192, 64);
    twc_kernel<<<(192*576+255)/256, 256, 0, stream>>>(c2w, c2T, 60, 180, 64, 192);

    ln_kernel<float><<<16384, 256, 0, stream>>>(x, n1g, n1b, xn);

    // conv1: M=65536, K=9*192, N=60 (+GELU) -> y1
    mgemm_kernel<1, 2, 192, 180><<<dim3(256, 1), 256, 0, stream>>>(
        xn, c1T, c1b, y1, 60, 1728, 0, 0, nullptr, nullptr, nullptr);
    // conv2: M=65536, K=9*64, N=180 -> resbuf (y2)
    mgemm_kernel<0, 2, 64, 60><<<dim3(256, 3), 256, 0, stream>>>(
        y1, c2T, c2b, resbuf, 180, 576, 0, 0, nullptr, nullptr, nullptr);
    pool_kernel<<<256, 192, 0, stream>>>(resbuf, pooled);
    ca_kernel<<<4, 192, 0, stream>>>(pooled, ca1w, ca1b, ca2w, ca2b, aab);

    for (int ch = 0; ch < CH_; ch++){
        int row0 = ch * CROWS_;
        mgemm_kernel<0, 1, 0, 0><<<dim3(CROWS_/256, 9), 256, 0, stream>>>(
            xn, qkvT, qkv_b, qkvb, 540, 192, row0, 180, nullptr, nullptr, nullptr);
        attn_kernel<<<CWIN_ * NH_, 128, 0, stream>>>(qkvb, biasT, attn_o);
        mgemm_kernel<3, 0, 0, 0><<<dim3(CROWS_/256, 3), 256, 0, stream>>>(
            attn_o, projT, proj_b, resbuf, 180, 192, row0, 180, x, nullptr, aab);
    }

    ln_kernel<bf16><<<16384, 256, 0, stream>>>(resbuf, n2g, n2b, xn);  // xn2

    for (int ch = 0; ch < CH_; ch++){
        size_t off = (size_t)ch * CROWS_ * C_;
        mgemm_kernel<1, 0, 0, 0><<<dim3(CROWS_/256, 12), 256, 0, stream>>>(
            xn + off, fc1T, fc1b, hbuf, 720, 192, 0, 180, nullptr, nullptr, nullptr);
        mgemm_kernel<2, 0, 0, 0><<<dim3(CROWS_/256, 3), 256, 0, stream>>>(
            hbuf, fc2T, fc2b, (float*)d_out + off, 180, 736, 0, 720,
            nullptr, resbuf + off, nullptr);
    }
}

// Round 5
// 903.899 us; speedup vs baseline: 5.7699x; 1.3674x over previous
//
#include <hip/hip_runtime.h>
#include <hip/hip_bf16.h>
#include <math.h>

typedef __hip_bfloat16 bf16;

#define B_    4
#define C_    180
#define ROWS_ 65536   // B*H*W
#define NH_   6
#define HD_   30
#define NT_   256     // tokens per window
#define CC_   60      // conv mid channels
#define HID_  720
#define CH_   4       // row chunks
#define CROWS_ 16384  // rows per chunk
#define CWIN_  64     // windows per chunk
#define ATT_SCALE 0.18257418583505536f  // 30^-0.5

typedef short  short4v __attribute__((ext_vector_type(4)));
typedef short  short8v __attribute__((ext_vector_type(8)));
typedef __bf16 bf16x8  __attribute__((ext_vector_type(8)));
typedef float  f32x4   __attribute__((ext_vector_type(4)));

__device__ __forceinline__ float b2f(bf16 v){ return __bfloat162float(v); }
__device__ __forceinline__ bf16  f2b(float v){ return __float2bfloat16(v); }
__device__ __forceinline__ float ldf(const bf16* p){ return __bfloat162float(*p); }
__device__ __forceinline__ float ldf(const float* p){ return *p; }
__device__ __forceinline__ float gelu_f(float v){
    return 0.5f * v * (1.0f + erff(v * 0.70710678118654752440f));
}
__device__ __forceinline__ f32x4 mfma16(short8v a, short8v b, f32x4 c){
    return __builtin_amdgcn_mfma_f32_16x16x32_bf16(
        __builtin_bit_cast(bf16x8, a), __builtin_bit_cast(bf16x8, b), c, 0, 0, 0);
}
__device__ __forceinline__ short8v cat44(short4v lo, short4v hi){
    return short8v{lo[0],lo[1],lo[2],lo[3],hi[0],hi[1],hi[2],hi[3]};
}

// window-ordered row r -> natural row
__device__ __forceinline__ int inv_win(int r){
    int b = r >> 14, w6 = (r >> 8) & 63, t = r & 255;
    int py = ((w6 >> 3) << 4) + (t >> 4);
    int px = ((w6 & 7) << 4) + (t & 15);
    return (b << 14) + (py << 7) + px;
}

// ---------------- LayerNorm: one wave per row of 180 ----------------
template<typename TIN>
__global__ __launch_bounds__(256) void ln_kernel(const TIN* __restrict__ xin,
        const float* __restrict__ gw, const float* __restrict__ gb,
        bf16* __restrict__ xn)
{
    int row  = blockIdx.x * 4 + (threadIdx.x >> 6);
    int lane = threadIdx.x & 63;
    const TIN* xp = xin + (size_t)row * C_;
    float v0 = ldf(xp + lane);
    float v1 = ldf(xp + lane + 64);
    float v2 = (lane < 52) ? ldf(xp + lane + 128) : 0.f;
    float s  = v0 + v1 + v2;
    float sq = v0*v0 + v1*v1 + v2*v2;
    for (int off = 32; off > 0; off >>= 1){
        s  += __shfl_xor(s,  off);
        sq += __shfl_xor(sq, off);
    }
    float mu  = s * (1.f / 180.f);
    float inv = rsqrtf(sq * (1.f / 180.f) - mu * mu + 1e-5f);
    size_t ro = (size_t)row * C_;
    #pragma unroll
    for (int e = 0; e < 3; e++){
        int c = lane + e * 64;
        if (c < C_){
            float v = (e == 0) ? v0 : (e == 1 ? v1 : v2);
            xn[ro + c] = f2b((v - mu) * inv * gw[c] + gb[c]);
        }
    }
}

// ---------------- weight transpose: W[K][N] -> BT[NP][KP] bf16, zero-padded ----
__global__ __launch_bounds__(256) void twt_kernel(const float* __restrict__ w,
        bf16* __restrict__ bt, int K, int N, int KP, int NP)
{
    int idx = blockIdx.x * 256 + threadIdx.x;
    if (idx >= NP * KP) return;
    int n = idx / KP, k = idx % KP;
    float v = (n < N && k < K) ? w[(size_t)k * N + n] : 0.f;
    bt[idx] = f2b(v);
}
// conv weight: w[((seg*CIN+ci))*N + n] -> BT[NP][9*SEGP]
__global__ __launch_bounds__(256) void twc_kernel(const float* __restrict__ w,
        bf16* __restrict__ bt, int CIN, int N, int SEGP, int NP)
{
    int KP = 9 * SEGP;
    int idx = blockIdx.x * 256 + threadIdx.x;
    if (idx >= NP * KP) return;
    int n = idx / KP, kk = idx % KP;
    int seg = kk / SEGP, ci = kk - seg * SEGP;
    float v = (n < N && ci < CIN) ? w[((size_t)seg * CIN + ci) * N + n] : 0.f;
    bt[idx] = f2b(v);
}

// ---------------- adaptive avg pool partials ----------------
__global__ __launch_bounds__(192) void pool_kernel(const bf16* __restrict__ y2,
                                                   float* __restrict__ pooled)
{
    int b = blockIdx.x >> 6;
    int chunk = blockIdx.x & 63;
    int c = threadIdx.x;
    if (c >= C_) return;
    const bf16* p = y2 + ((size_t)(b << 14) + (chunk << 8)) * C_ + c;
    float s = 0.f;
    for (int i = 0; i < 256; i++) s += b2f(p[(size_t)i * C_]);
    atomicAdd(&pooled[b * C_ + c], s);
}

// ---------------- channel attention tiny MLP ----------------
__global__ __launch_bounds__(192) void ca_kernel(const float* __restrict__ pooled,
        const float* __restrict__ w1, const float* __restrict__ b1,
        const float* __restrict__ w2, const float* __restrict__ b2v,
        float* __restrict__ aout)
{
    __shared__ float t[NH_];
    int b = blockIdx.x, tid = threadIdx.x;
    if (tid < 6){
        float s = b1[tid];
        for (int c = 0; c < C_; c++)
            s += pooled[b * C_ + c] * (1.f / 16384.f) * w1[c * 6 + tid];
        t[tid] = fmaxf(s, 0.f);
    }
    __syncthreads();
    if (tid < C_){
        float s = b2v[tid];
        #pragma unroll
        for (int j = 0; j < 6; j++) s += t[j] * w2[j * C_ + tid];
        aout[b * C_ + tid] = 1.f / (1.f + __expf(-s));
    }
}

// ---------------- relative position bias table (bf16) ----------------
__global__ __launch_bounds__(256) void rpb_kernel(const float* __restrict__ rpb,
        const int* __restrict__ rpi, bf16* __restrict__ biasT)
{
    int idx = blockIdx.x * 256 + threadIdx.x;     // h*65536 + i*256 + j
    int h = idx >> 16, ij = idx & 65535;
    biasT[idx] = f2b(rpb[rpi[ij] * 6 + h]);
}

// ================= unified MFMA GEMM =================
template<int EPI, int MODE, int SEGP, int CSTR>
__global__ __launch_bounds__(256) void mgemm_kernel(const bf16* __restrict__ A,
        const bf16* __restrict__ BT, const float* __restrict__ bias,
        void* outp, int N, int KP, int row0, int ldA,
        const float* __restrict__ xres, const bf16* __restrict__ resb,
        const float* __restrict__ aab)
{
    __shared__ short As[256 * 32];
    __shared__ short Bs[64 * 32];
    int tid = threadIdx.x;
    int gm0 = blockIdx.x * 256;
    int n0  = blockIdx.y * 64;
    f32x4 acc[4][4];
    #pragma unroll
    for (int i = 0; i < 4; i++)
        #pragma unroll
        for (int j = 0; j < 4; j++)
            acc[i][j] = (f32x4)0.f;

    int r_ = tid >> 2;
    int q_ = tid & 3;
    int lane = tid & 63, wv = tid >> 6;
    int quad = lane >> 4, l15 = lane & 15;
    int nch = KP >> 5;

    for (int kc = 0; kc < nch; kc++){
        int k0 = kc * 32;
        int gk = k0 + q_ * 8;
        #pragma unroll
        for (int s = 0; s < 4; s++){
            int r = r_ + s * 64;
            short8v val;
            if (MODE == 2){
                int mg = gm0 + r;
                int bb = mg >> 14, p = mg & 16383;
                int py = p >> 7, px = p & 127;
                int seg = k0 / SEGP;
                int kh = seg / 3, kw = seg - kh * 3;
                int ci = gk - seg * SEGP;
                int y = py + kh - 1, x = px + kw - 1;
                if ((unsigned)y < 128u && (unsigned)x < 128u){
                    const bf16* ap = A + ((size_t)(bb << 14) + (y << 7) + x) * CSTR + ci;
                    val = cat44(*(const short4v*)ap, *(const short4v*)(ap + 4));
                } else {
                    val = short8v{0,0,0,0,0,0,0,0};
                }
            } else {
                int arow = gm0 + r;
                if (MODE == 1) arow = inv_win(row0 + arow);
                const bf16* ap = A + (size_t)arow * ldA + gk;
                val = cat44(*(const short4v*)ap, *(const short4v*)(ap + 4));
            }
            int pp = q_ ^ ((r >> 1) & 3);
            *(short8v*)&As[r * 32 + pp * 8] = val;
        }
        {
            int n = tid >> 2;
            const bf16* bp = BT + (size_t)(n0 + n) * KP + gk;
            int pp = q_ ^ ((n >> 1) & 3);
            *(short8v*)&Bs[n * 32 + pp * 8] =
                cat44(*(const short4v*)bp, *(const short4v*)(bp + 4));
        }
        __syncthreads();
        short8v af[4], bfr[4];
        #pragma unroll
        for (int i = 0; i < 4; i++){
            int r = wv * 64 + i * 16 + l15;
            int pp = quad ^ ((r >> 1) & 3);
            af[i] = *(const short8v*)&As[r * 32 + pp * 8];
        }
        #pragma unroll
        for (int j = 0; j < 4; j++){
            int n = j * 16 + l15;
            int pp = quad ^ ((n >> 1) & 3);
            bfr[j] = *(const short8v*)&Bs[n * 32 + pp * 8];
        }
        #pragma unroll
        for (int i = 0; i < 4; i++)
            #pragma unroll
            for (int j = 0; j < 4; j++)
                acc[i][j] = mfma16(af[i], bfr[j], acc[i][j]);
        __syncthreads();
    }

    #pragma unroll
    for (int i = 0; i < 4; i++){
        #pragma unroll
        for (int reg = 0; reg < 4; reg++){
            int gr = gm0 + wv * 64 + i * 16 + quad * 4 + reg;
            #pragma unroll
            for (int j = 0; j < 4; j++){
                int gc = n0 + j * 16 + l15;
                if (gc >= N) continue;
                float v = acc[i][j][reg] + bias[gc];
                if (EPI == 1) v = gelu_f(v);
                if (EPI == 0 || EPI == 1){
                    ((bf16*)outp)[(size_t)gr * N + gc] = f2b(v);
                } else if (EPI == 2){
                    size_t oi = (size_t)gr * N + gc;
                    ((float*)outp)[oi] = v + b2f(resb[oi]);
                } else {
                    int nr = inv_win(row0 + gr);
                    size_t oi = (size_t)nr * C_ + gc;
                    bf16* ob = (bf16*)outp;
                    v += xres[oi] + b2f(ob[oi]) * aab[(nr >> 14) * C_ + gc] * 0.01f;
                    ob[oi] = f2b(v);
                }
            }
        }
    }
}

// ================= MFMA windowed attention =================
// Block = (chunk-local window, head), 256 threads / 4 waves.
// S = Q@K^T via mfma (k=32, d padded), softmax without max-subtraction
// (scores are O(0.1)), accumulated over two 128-token k-halves:
//   l += sum(exp), O += P@V  (linear, no rescale needed).
// LDS: Ks[256][36] (token-major, d 30/31 zeroed), Vt[32][260] (d-major),
//      P[64][132] (wave-private rows -> no barrier for the P round-trip).
#define KS_STR 36
#define VT_STR 260
#define P_STR  132
__global__ __launch_bounds__(256) void attn_kernel(const bf16* __restrict__ qkv,
        const bf16* __restrict__ biasT, bf16* __restrict__ attn_o)
{
    __shared__ short lds[256*KS_STR + 32*VT_STR + 64*P_STR];  // 51,968 B
    short* Ks = lds;
    short* Vt = lds + 256*KS_STR;
    bf16*  Pp = (bf16*)(lds + 256*KS_STR + 32*VT_STR);

    int tid = threadIdx.x;
    int win = blockIdx.x / NH_;
    int h   = blockIdx.x % NH_;
    const bf16* wbase = qkv + (size_t)win * NT_ * 540;

    // ---- stage K (token-major, zero-pad d>=30) and V^T ----
    {
        int t = tid;
        const bf16* row = wbase + (size_t)t * 540;
        const uint* kp = (const uint*)(row + 180 + h * HD_);
        const uint* vp = (const uint*)(row + 360 + h * HD_);
        uint* kd = (uint*)(Ks + t * KS_STR);
        #pragma unroll
        for (int i = 0; i < 15; i++) kd[i] = kp[i];
        kd[15] = 0; kd[16] = 0; kd[17] = 0;
        #pragma unroll
        for (int i = 0; i < 15; i++){
            uint w = vp[i];
            Vt[(2*i  ) * VT_STR + t] = (short)(w & 0xffff);
            Vt[(2*i+1) * VT_STR + t] = (short)(w >> 16);
        }
        Vt[30 * VT_STR + t] = 0;
        Vt[31 * VT_STR + t] = 0;
    }
    __syncthreads();

    int lane = tid & 63, wv = tid >> 6;
    int quad = lane >> 4, l15 = lane & 15;
    const bf16* qbase = wbase + h * HD_;
    const bf16* brow  = biasT + (size_t)h * 65536;

    for (int qb = 0; qb < 4; qb++){
        int qrow = qb * 64 + wv * 16 + l15;          // A-frag row (m = l15)
        short8v af;
        {
            const uint* qp = (const uint*)(qbase + (size_t)qrow * 540 + quad * 8);
            union { uint u[4]; short8v v; } qa;
            qa.u[0] = qp[0]; qa.u[1] = qp[1]; qa.u[2] = qp[2]; qa.u[3] = qp[3];
            af = qa.v;     // d 30,31 junk is OK: K rows zero-padded there
        }
        f32x4 Oacc[2];
        Oacc[0] = (f32x4)0.f; Oacc[1] = (f32x4)0.f;
        float lsum[4] = {0.f, 0.f, 0.f, 0.f};

        for (int kh = 0; kh < 2; kh++){
            // ---- S = Q@K^T for 16q x 128k ----
            f32x4 s[8];
            #pragma unroll
            for (int jt = 0; jt < 8; jt++) s[jt] = (f32x4)0.f;
            #pragma unroll
            for (int jt = 0; jt < 8; jt++){
                int tok = kh * 128 + jt * 16 + l15;
                const short* kp = Ks + tok * KS_STR + quad * 8;
                short8v bfr = cat44(*(const short4v*)kp, *(const short4v*)(kp + 4));
                s[jt] = mfma16(af, bfr, s[jt]);
            }
            // ---- scale + bias + exp, write P, row partial sums ----
            float part[4] = {0.f, 0.f, 0.f, 0.f};
            #pragma unroll
            for (int jt = 0; jt < 8; jt++){
                int j = kh * 128 + jt * 16 + l15;
                #pragma unroll
                for (int reg = 0; reg < 4; reg++){
                    int i = qb * 64 + wv * 16 + quad * 4 + reg;
                    float v = s[jt][reg] * ATT_SCALE + b2f(brow[(size_t)i * 256 + j]);
                    float p = __expf(v);
                    part[reg] += p;
                    Pp[(wv * 16 + quad * 4 + reg) * P_STR + jt * 16 + l15] = f2b(p);
                }
            }
            #pragma unroll
            for (int m = 1; m < 16; m <<= 1){
                #pragma unroll
                for (int reg = 0; reg < 4; reg++)
                    part[reg] += __shfl_xor(part[reg], m);
            }
            #pragma unroll
            for (int reg = 0; reg < 4; reg++) lsum[reg] += part[reg];
            // ---- O += P @ V (wave-private P rows) ----
            #pragma unroll
            for (int kc = 0; kc < 4; kc++){
                const short* pa_p = (const short*)Pp + (wv * 16 + l15) * P_STR
                                    + kc * 32 + quad * 8;
                short8v pa = cat44(*(const short4v*)pa_p, *(const short4v*)(pa_p + 4));
                #pragma unroll
                for (int jt2 = 0; jt2 < 2; jt2++){
                    const short* vb_p = Vt + (jt2 * 16 + l15) * VT_STR
                                        + kh * 128 + kc * 32 + quad * 8;
                    short8v vb = cat44(*(const short4v*)vb_p, *(const short4v*)(vb_p + 4));
                    Oacc[jt2] = mfma16(pa, vb, Oacc[jt2]);
                }
            }
        }
        // ---- normalize + store ----
        #pragma unroll
        for (int jt2 = 0; jt2 < 2; jt2++){
            int d = jt2 * 16 + l15;
            if (d < HD_){
                #pragma unroll
                for (int reg = 0; reg < 4; reg++){
                    int qr = qb * 64 + wv * 16 + quad * 4 + reg;
                    attn_o[((size_t)win * NT_ + qr) * C_ + h * HD_ + d] =
                        f2b(Oacc[jt2][reg] / lsum[reg]);
                }
            }
        }
    }
}

extern "C" void kernel_launch(void* const* d_in, const int* in_sizes, int n_in,
                              void* d_out, int out_size, void* d_ws, size_t ws_size,
                              hipStream_t stream)
{
    const float* x      = (const float*)d_in[0];
    const int*   rpi    = (const int*)  d_in[1];
    const float* n1g    = (const float*)d_in[6];
    const float* n1b    = (const float*)d_in[7];
    const float* qkv_w  = (const float*)d_in[8];
    const float* qkv_b  = (const float*)d_in[9];
    const float* rpb    = (const float*)d_in[10];
    const float* proj_w = (const float*)d_in[11];
    const float* proj_b = (const float*)d_in[12];
    const float* c1w    = (const float*)d_in[13];
    const float* c1b    = (const float*)d_in[14];
    const float* c2w    = (const float*)d_in[15];
    const float* c2b    = (const float*)d_in[16];
    const float* ca1w   = (const float*)d_in[17];
    const float* ca1b   = (const float*)d_in[18];
    const float* ca2w   = (const float*)d_in[19];
    const float* ca2b   = (const float*)d_in[20];
    const float* n2g    = (const float*)d_in[21];
    const float* n2b    = (const float*)d_in[22];
    const float* fc1w   = (const float*)d_in[23];
    const float* fc1b   = (const float*)d_in[24];
    const float* fc2w   = (const float*)d_in[25];
    const float* fc2b   = (const float*)d_in[26];

    // ---- workspace layout (~69.5 MB) ----
    char* ws = (char*)d_ws;
    bf16*  slab   = (bf16*)(ws);
    bf16*  y1     = slab;
    bf16*  qkvb   = slab;
    bf16*  attn_o = (bf16*)(ws + 17694720);
    bf16*  hbuf   = slab;
    bf16*  xn     = (bf16*)(ws + 23592960);
    bf16*  resbuf = (bf16*)(ws + 47185920);
    bf16*  biasT  = (bf16*)(ws + 70778880);
    bf16*  qkvT   = (bf16*)(ws + 71565312);
    bf16*  projT  = (bf16*)(ws + 71786496);
    bf16*  fc1T   = (bf16*)(ws + 71860224);
    bf16*  fc2T   = (bf16*)(ws + 72155136);
    bf16*  c1T    = (bf16*)(ws + 72437760);
    bf16*  c2T    = (bf16*)(ws + 72658944);
    float* pooled = (float*)(ws + 72880128);
    float* aab    = (float*)(ws + 72883008);

    hipMemsetAsync(pooled, 0, B_ * C_ * sizeof(float), stream);
    rpb_kernel<<<1536, 256, 0, stream>>>(rpb, rpi, biasT);
    twt_kernel<<<(576*192+255)/256, 256, 0, stream>>>(qkv_w, qkvT, 180, 540, 192, 576);
    twt_kernel<<<(192*192+255)/256, 256, 0, stream>>>(proj_w, projT, 180, 180, 192, 192);
    twt_kernel<<<(768*192+255)/256, 256, 0, stream>>>(fc1w, fc1T, 180, 720, 192, 768);
    twt_kernel<<<(192*736+255)/256, 256, 0, stream>>>(fc2w, fc2T, 720, 180, 736, 192);
    twc_kernel<<<(64*1728+255)/256, 256, 0, stream>>>(c1w, c1T, 180, 60, 192, 64);
    twc_kernel<<<(192*576+255)/256, 256, 0, stream>>>(c2w, c2T, 60, 180, 64, 192);

    ln_kernel<float><<<16384, 256, 0, stream>>>(x, n1g, n1b, xn);

    mgemm_kernel<1, 2, 192, 180><<<dim3(256, 1), 256, 0, stream>>>(
        xn, c1T, c1b, y1, 60, 1728, 0, 0, nullptr, nullptr, nullptr);
    mgemm_kernel<0, 2, 64, 60><<<dim3(256, 3), 256, 0, stream>>>(
        y1, c2T, c2b, resbuf, 180, 576, 0, 0, nullptr, nullptr, nullptr);
    pool_kernel<<<256, 192, 0, stream>>>(resbuf, pooled);
    ca_kernel<<<4, 192, 0, stream>>>(pooled, ca1w, ca1b, ca2w, ca2b, aab);

    for (int ch = 0; ch < CH_; ch++){
        int row0 = ch * CROWS_;
        mgemm_kernel<0, 1, 0, 0><<<dim3(CROWS_/256, 9), 256, 0, stream>>>(
            xn, qkvT, qkv_b, qkvb, 540, 192, row0, 180, nullptr, nullptr, nullptr);
        attn_kernel<<<CWIN_ * NH_, 256, 0, stream>>>(qkvb, biasT, attn_o);
        mgemm_kernel<3, 0, 0, 0><<<dim3(CROWS_/256, 3), 256, 0, stream>>>(
            attn_o, projT, proj_b, resbuf, 180, 192, row0, 180, x, nullptr, aab);
    }

    ln_kernel<bf16><<<16384, 256, 0, stream>>>(resbuf, n2g, n2b, xn);

    for (int ch = 0; ch < CH_; ch++){
        size_t off = (size_t)ch * CROWS_ * C_;
        mgemm_kernel<1, 0, 0, 0><<<dim3(CROWS_/256, 12), 256, 0, stream>>>(
            xn + off, fc1T, fc1b, hbuf, 720, 192, 0, 180, nullptr, nullptr, nullptr);
        mgemm_kernel<2, 0, 0, 0><<<dim3(CROWS_/256, 3), 256, 0, stream>>>(
            hbuf, fc2T, fc2b, (float*)d_out + off, 180, 736, 0, 720,
            nullptr, resbuf + off, nullptr);
    }
}

// Round 6
// 598.287 us; speedup vs baseline: 8.7172x; 1.5108x over previous
//
#include <hip/hip_runtime.h>
#include <hip/hip_bf16.h>
#include <math.h>

typedef __hip_bfloat16 bf16;

#define B_    4
#define C_    180
#define ROWS_ 65536   // B*H*W
#define NH_   6
#define HD_   30
#define NT_   256     // tokens per window
#define CC_   60      // conv mid channels
#define HID_  720
#define ATT_SCALE 0.18257418583505536f  // 30^-0.5

typedef short  short4v __attribute__((ext_vector_type(4)));
typedef short  short8v __attribute__((ext_vector_type(8)));
typedef __bf16 bf16x8  __attribute__((ext_vector_type(8)));
typedef float  f32x4   __attribute__((ext_vector_type(4)));

__device__ __forceinline__ float b2f(bf16 v){ return __bfloat162float(v); }
__device__ __forceinline__ bf16  f2b(float v){ return __float2bfloat16(v); }
__device__ __forceinline__ float ldf(const bf16* p){ return __bfloat162float(*p); }
__device__ __forceinline__ float ldf(const float* p){ return *p; }
__device__ __forceinline__ float gelu_f(float v){
    return 0.5f * v * (1.0f + erff(v * 0.70710678118654752440f));
}
__device__ __forceinline__ f32x4 mfma16(short8v a, short8v b, f32x4 c){
    return __builtin_amdgcn_mfma_f32_16x16x32_bf16(
        __builtin_bit_cast(bf16x8, a), __builtin_bit_cast(bf16x8, b), c, 0, 0, 0);
}
__device__ __forceinline__ short8v cat44(short4v lo, short4v hi){
    return short8v{lo[0],lo[1],lo[2],lo[3],hi[0],hi[1],hi[2],hi[3]};
}

// window-ordered row r -> natural row
__device__ __forceinline__ int inv_win(int r){
    int b = r >> 14, w6 = (r >> 8) & 63, t = r & 255;
    int py = ((w6 >> 3) << 4) + (t >> 4);
    int px = ((w6 & 7) << 4) + (t & 15);
    return (b << 14) + (py << 7) + px;
}

// ---------------- LayerNorm: one wave per row of 180 ----------------
template<typename TIN>
__global__ __launch_bounds__(256) void ln_kernel(const TIN* __restrict__ xin,
        const float* __restrict__ gw, const float* __restrict__ gb,
        bf16* __restrict__ xn)
{
    int row  = blockIdx.x * 4 + (threadIdx.x >> 6);
    int lane = threadIdx.x & 63;
    const TIN* xp = xin + (size_t)row * C_;
    float v0 = ldf(xp + lane);
    float v1 = ldf(xp + lane + 64);
    float v2 = (lane < 52) ? ldf(xp + lane + 128) : 0.f;
    float s  = v0 + v1 + v2;
    float sq = v0*v0 + v1*v1 + v2*v2;
    for (int off = 32; off > 0; off >>= 1){
        s  += __shfl_xor(s,  off);
        sq += __shfl_xor(sq, off);
    }
    float mu  = s * (1.f / 180.f);
    float inv = rsqrtf(sq * (1.f / 180.f) - mu * mu + 1e-5f);
    size_t ro = (size_t)row * C_;
    #pragma unroll
    for (int e = 0; e < 3; e++){
        int c = lane + e * 64;
        if (c < C_){
            float v = (e == 0) ? v0 : (e == 1 ? v1 : v2);
            xn[ro + c] = f2b((v - mu) * inv * gw[c] + gb[c]);
        }
    }
}

// ---------------- weight transpose: W[K][N] -> BT[NP][KP] bf16, zero-padded ----
__global__ __launch_bounds__(256) void twt_kernel(const float* __restrict__ w,
        bf16* __restrict__ bt, int K, int N, int KP, int NP)
{
    int idx = blockIdx.x * 256 + threadIdx.x;
    if (idx >= NP * KP) return;
    int n = idx / KP, k = idx % KP;
    float v = (n < N && k < K) ? w[(size_t)k * N + n] : 0.f;
    bt[idx] = f2b(v);
}
// conv weight: w[((seg*CIN+ci))*N + n] -> BT[NP][9*SEGP]
__global__ __launch_bounds__(256) void twc_kernel(const float* __restrict__ w,
        bf16* __restrict__ bt, int CIN, int N, int SEGP, int NP)
{
    int KP = 9 * SEGP;
    int idx = blockIdx.x * 256 + threadIdx.x;
    if (idx >= NP * KP) return;
    int n = idx / KP, kk = idx % KP;
    int seg = kk / SEGP, ci = kk - seg * SEGP;
    float v = (n < N && ci < CIN) ? w[((size_t)seg * CIN + ci) * N + n] : 0.f;
    bt[idx] = f2b(v);
}

// ---------------- adaptive avg pool partials ----------------
__global__ __launch_bounds__(192) void pool_kernel(const bf16* __restrict__ y2,
                                                   float* __restrict__ pooled)
{
    int b = blockIdx.x >> 6;
    int chunk = blockIdx.x & 63;
    int c = threadIdx.x;
    if (c >= C_) return;
    const bf16* p = y2 + ((size_t)(b << 14) + (chunk << 8)) * C_ + c;
    float s = 0.f;
    for (int i = 0; i < 256; i++) s += b2f(p[(size_t)i * C_]);
    atomicAdd(&pooled[b * C_ + c], s);
}

// ---------------- channel attention tiny MLP ----------------
__global__ __launch_bounds__(192) void ca_kernel(const float* __restrict__ pooled,
        const float* __restrict__ w1, const float* __restrict__ b1,
        const float* __restrict__ w2, const float* __restrict__ b2v,
        float* __restrict__ aout)
{
    __shared__ float t[NH_];
    int b = blockIdx.x, tid = threadIdx.x;
    if (tid < 6){
        float s = b1[tid];
        for (int c = 0; c < C_; c++)
            s += pooled[b * C_ + c] * (1.f / 16384.f) * w1[c * 6 + tid];
        t[tid] = fmaxf(s, 0.f);
    }
    __syncthreads();
    if (tid < C_){
        float s = b2v[tid];
        #pragma unroll
        for (int j = 0; j < 6; j++) s += t[j] * w2[j * C_ + tid];
        aout[b * C_ + tid] = 1.f / (1.f + __expf(-s));
    }
}

// ---------------- relative position bias table (bf16) ----------------
__global__ __launch_bounds__(256) void rpb_kernel(const float* __restrict__ rpb,
        const int* __restrict__ rpi, bf16* __restrict__ biasT)
{
    int idx = blockIdx.x * 256 + threadIdx.x;     // h*65536 + i*256 + j
    int h = idx >> 16, ij = idx & 65535;
    biasT[idx] = f2b(rpb[rpi[ij] * 6 + h]);
}

// ================= unified MFMA GEMM, 128x64 tile, dbuf-pipelined K-loop =========
// 4 waves; wave computes 32x64 via 2x4 mfma_f32_16x16x32_bf16.
// MODE 0: A[arow*ldA + k]   1: arow = inv_win(row0+row)   2: conv gather
// EPI  0: bias->bf16  1: bias+GELU->bf16  2: bias+resb->fp32  3: scatter-resid in place
template<int EPI, int MODE, int SEGP, int CSTR>
__global__ __launch_bounds__(256) void mgemm_kernel(const bf16* __restrict__ A,
        const bf16* __restrict__ BT, const float* __restrict__ bias,
        void* outp, int N, int KP, int row0, int ldA,
        const float* __restrict__ xres, const bf16* __restrict__ resb,
        const float* __restrict__ aab)
{
    __shared__ short As[2][128 * 32];
    __shared__ short Bs[2][64 * 32];
    int tid = threadIdx.x;
    int gm0 = blockIdx.x * 128;
    int n0  = blockIdx.y * 64;
    f32x4 acc[2][4];
    #pragma unroll
    for (int i = 0; i < 2; i++)
        #pragma unroll
        for (int j = 0; j < 4; j++)
            acc[i][j] = (f32x4)0.f;

    int lane = tid & 63, wv = tid >> 6;
    int quad = lane >> 4, l15 = lane & 15;
    int ar = tid >> 1, aq = (tid & 1) * 2;   // A: row 0..127, two 8-elem k-groups
    int bn = tid >> 2, bq = tid & 3;         // B: n 0..63, one 8-elem k-group
    int nch = KP >> 5;

    auto loadA8 = [&](int kc, int s) -> short8v {
        int k0 = kc * 32;
        int gk = k0 + (aq + s) * 8;
        if (MODE == 2){
            int mg = gm0 + ar;
            int bb = mg >> 14, p = mg & 16383;
            int py = p >> 7, px = p & 127;
            int seg = k0 / SEGP;
            int kh = seg / 3, kw = seg - kh * 3;
            int ci = gk - seg * SEGP;
            int y = py + kh - 1, xx = px + kw - 1;
            if ((unsigned)y < 128u && (unsigned)xx < 128u){
                const bf16* ap = A + ((size_t)(bb << 14) + (y << 7) + xx) * CSTR + ci;
                return cat44(*(const short4v*)ap, *(const short4v*)(ap + 4));
            }
            return short8v{0,0,0,0,0,0,0,0};
        } else {
            int arow = gm0 + ar;
            if (MODE == 1) arow = inv_win(row0 + arow);
            const bf16* ap = A + (size_t)arow * ldA + gk;
            return cat44(*(const short4v*)ap, *(const short4v*)(ap + 4));
        }
    };
    auto loadB8 = [&](int kc) -> short8v {
        const bf16* bp = BT + (size_t)(n0 + bn) * KP + kc * 32 + bq * 8;
        return cat44(*(const short4v*)bp, *(const short4v*)(bp + 4));
    };
    auto storeA = [&](int buf, short8v v0, short8v v1){
        int base = ar * 32;
        int sw = (ar >> 1) & 3;
        *(short8v*)&As[buf][base + (aq ^ sw) * 8]       = v0;
        *(short8v*)&As[buf][base + ((aq + 1) ^ sw) * 8] = v1;
    };
    auto storeB = [&](int buf, short8v v){
        *(short8v*)&Bs[buf][bn * 32 + (bq ^ ((bn >> 1) & 3)) * 8] = v;
    };

    {   // prologue: stage chunk 0 into buffer 0
        short8v a0 = loadA8(0, 0), a1 = loadA8(0, 1), b0 = loadB8(0);
        storeA(0, a0, a1); storeB(0, b0);
    }
    for (int kc = 0; kc < nch; kc++){
        int cur = kc & 1;
        __syncthreads();
        short8v na0, na1, nb0;
        bool more = (kc + 1 < nch);
        if (more){ na0 = loadA8(kc + 1, 0); na1 = loadA8(kc + 1, 1); nb0 = loadB8(kc + 1); }
        short8v af[2], bfr[4];
        #pragma unroll
        for (int i = 0; i < 2; i++){
            int r = wv * 32 + i * 16 + l15;
            int pp = quad ^ ((r >> 1) & 3);
            af[i] = *(const short8v*)&As[cur][r * 32 + pp * 8];
        }
        #pragma unroll
        for (int j = 0; j < 4; j++){
            int n = j * 16 + l15;
            int pp = quad ^ ((n >> 1) & 3);
            bfr[j] = *(const short8v*)&Bs[cur][n * 32 + pp * 8];
        }
        #pragma unroll
        for (int i = 0; i < 2; i++)
            #pragma unroll
            for (int j = 0; j < 4; j++)
                acc[i][j] = mfma16(af[i], bfr[j], acc[i][j]);
        if (more){ storeA(cur ^ 1, na0, na1); storeB(cur ^ 1, nb0); }
    }

    #pragma unroll
    for (int i = 0; i < 2; i++){
        #pragma unroll
        for (int reg = 0; reg < 4; reg++){
            int gr = gm0 + wv * 32 + i * 16 + quad * 4 + reg;
            #pragma unroll
            for (int j = 0; j < 4; j++){
                int gc = n0 + j * 16 + l15;
                if (gc >= N) continue;
                float v = acc[i][j][reg] + bias[gc];
                if (EPI == 1) v = gelu_f(v);
                if (EPI == 0 || EPI == 1){
                    ((bf16*)outp)[(size_t)gr * N + gc] = f2b(v);
                } else if (EPI == 2){
                    size_t oi = (size_t)gr * N + gc;
                    ((float*)outp)[oi] = v + b2f(resb[oi]);
                } else {
                    int nr = inv_win(row0 + gr);
                    size_t oi = (size_t)nr * C_ + gc;
                    bf16* ob = (bf16*)outp;
                    v += xres[oi] + b2f(ob[oi]) * aab[(nr >> 14) * C_ + gc] * 0.01f;
                    ob[oi] = f2b(v);
                }
            }
        }
    }
}

// ================= MFMA windowed attention =================
#define KS_STR 36
#define VT_STR 260
#define P_STR  132
__global__ __launch_bounds__(256) void attn_kernel(const bf16* __restrict__ qkv,
        const bf16* __restrict__ biasT, bf16* __restrict__ attn_o)
{
    __shared__ short lds[256*KS_STR + 32*VT_STR + 64*P_STR];  // 51,968 B
    short* Ks = lds;
    short* Vt = lds + 256*KS_STR;
    bf16*  Pp = (bf16*)(lds + 256*KS_STR + 32*VT_STR);

    int tid = threadIdx.x;
    int win = blockIdx.x / NH_;
    int h   = blockIdx.x % NH_;
    const bf16* wbase = qkv + (size_t)win * NT_ * 540;

    {
        int t = tid;
        const bf16* row = wbase + (size_t)t * 540;
        const uint* kp = (const uint*)(row + 180 + h * HD_);
        const uint* vp = (const uint*)(row + 360 + h * HD_);
        uint* kd = (uint*)(Ks + t * KS_STR);
        #pragma unroll
        for (int i = 0; i < 15; i++) kd[i] = kp[i];
        kd[15] = 0; kd[16] = 0; kd[17] = 0;
        #pragma unroll
        for (int i = 0; i < 15; i++){
            uint w = vp[i];
            Vt[(2*i  ) * VT_STR + t] = (short)(w & 0xffff);
            Vt[(2*i+1) * VT_STR + t] = (short)(w >> 16);
        }
        Vt[30 * VT_STR + t] = 0;
        Vt[31 * VT_STR + t] = 0;
    }
    __syncthreads();

    int lane = tid & 63, wv = tid >> 6;
    int quad = lane >> 4, l15 = lane & 15;
    const bf16* qbase = wbase + h * HD_;
    const bf16* brow  = biasT + (size_t)h * 65536;

    for (int qb = 0; qb < 4; qb++){
        int qrow = qb * 64 + wv * 16 + l15;
        short8v af;
        {
            const uint* qp = (const uint*)(qbase + (size_t)qrow * 540 + quad * 8);
            union { uint u[4]; short8v v; } qa;
            qa.u[0] = qp[0]; qa.u[1] = qp[1]; qa.u[2] = qp[2]; qa.u[3] = qp[3];
            af = qa.v;
        }
        f32x4 Oacc[2];
        Oacc[0] = (f32x4)0.f; Oacc[1] = (f32x4)0.f;
        float lsum[4] = {0.f, 0.f, 0.f, 0.f};

        for (int kh = 0; kh < 2; kh++){
            f32x4 s[8];
            #pragma unroll
            for (int jt = 0; jt < 8; jt++) s[jt] = (f32x4)0.f;
            #pragma unroll
            for (int jt = 0; jt < 8; jt++){
                int tok = kh * 128 + jt * 16 + l15;
                const short* kp = Ks + tok * KS_STR + quad * 8;
                short8v bfr = cat44(*(const short4v*)kp, *(const short4v*)(kp + 4));
                s[jt] = mfma16(af, bfr, s[jt]);
            }
            float part[4] = {0.f, 0.f, 0.f, 0.f};
            #pragma unroll
            for (int jt = 0; jt < 8; jt++){
                int j = kh * 128 + jt * 16 + l15;
                #pragma unroll
                for (int reg = 0; reg < 4; reg++){
                    int i = qb * 64 + wv * 16 + quad * 4 + reg;
                    float v = s[jt][reg] * ATT_SCALE + b2f(brow[(size_t)i * 256 + j]);
                    float p = __expf(v);
                    part[reg] += p;
                    Pp[(wv * 16 + quad * 4 + reg) * P_STR + jt * 16 + l15] = f2b(p);
                }
            }
            #pragma unroll
            for (int m = 1; m < 16; m <<= 1){
                #pragma unroll
                for (int reg = 0; reg < 4; reg++)
                    part[reg] += __shfl_xor(part[reg], m);
            }
            #pragma unroll
            for (int reg = 0; reg < 4; reg++) lsum[reg] += part[reg];
            #pragma unroll
            for (int kc = 0; kc < 4; kc++){
                const short* pa_p = (const short*)Pp + (wv * 16 + l15) * P_STR
                                    + kc * 32 + quad * 8;
                short8v pa = cat44(*(const short4v*)pa_p, *(const short4v*)(pa_p + 4));
                #pragma unroll
                for (int jt2 = 0; jt2 < 2; jt2++){
                    const short* vb_p = Vt + (jt2 * 16 + l15) * VT_STR
                                        + kh * 128 + kc * 32 + quad * 8;
                    short8v vb = cat44(*(const short4v*)vb_p, *(const short4v*)(vb_p + 4));
                    Oacc[jt2] = mfma16(pa, vb, Oacc[jt2]);
                }
            }
        }
        #pragma unroll
        for (int jt2 = 0; jt2 < 2; jt2++){
            int d = jt2 * 16 + l15;
            if (d < HD_){
                #pragma unroll
                for (int reg = 0; reg < 4; reg++){
                    int qr = qb * 64 + wv * 16 + quad * 4 + reg;
                    attn_o[((size_t)win * NT_ + qr) * C_ + h * HD_ + d] =
                        f2b(Oacc[jt2][reg] / lsum[reg]);
                }
            }
        }
    }
}

extern "C" void kernel_launch(void* const* d_in, const int* in_sizes, int n_in,
                              void* d_out, int out_size, void* d_ws, size_t ws_size,
                              hipStream_t stream)
{
    const float* x      = (const float*)d_in[0];
    const int*   rpi    = (const int*)  d_in[1];
    const float* n1g    = (const float*)d_in[6];
    const float* n1b    = (const float*)d_in[7];
    const float* qkv_w  = (const float*)d_in[8];
    const float* qkv_b  = (const float*)d_in[9];
    const float* rpb    = (const float*)d_in[10];
    const float* proj_w = (const float*)d_in[11];
    const float* proj_b = (const float*)d_in[12];
    const float* c1w    = (const float*)d_in[13];
    const float* c1b    = (const float*)d_in[14];
    const float* c2w    = (const float*)d_in[15];
    const float* c2b    = (const float*)d_in[16];
    const float* ca1w   = (const float*)d_in[17];
    const float* ca1b   = (const float*)d_in[18];
    const float* ca2w   = (const float*)d_in[19];
    const float* ca2b   = (const float*)d_in[20];
    const float* n2g    = (const float*)d_in[21];
    const float* n2b    = (const float*)d_in[22];
    const float* fc1w   = (const float*)d_in[23];
    const float* fc1b   = (const float*)d_in[24];
    const float* fc2w   = (const float*)d_in[25];
    const float* fc2b   = (const float*)d_in[26];

    // ---- adaptive chunking: CH=2 needs ~96.5 MB, CH=4 needs ~72.9 MB ----
    size_t fixed = 23592960ull * 2 + 786432 + 1314816 + 5760;
    int CH = (ws_size >= (size_t)32768 * 1440 + fixed) ? 2 : 4;
    int CROWS = ROWS_ / CH;
    int CWIN  = CROWS / 256;
    size_t slab_sz = (size_t)CROWS * 1440;

    char* ws = (char*)d_ws;
    bf16*  slab   = (bf16*)(ws);
    bf16*  y1     = slab;
    bf16*  qkvb   = slab;
    bf16*  attn_o = (bf16*)(ws + (size_t)CROWS * 1080);
    bf16*  hbuf   = slab;
    bf16*  xn     = (bf16*)(ws + slab_sz);
    bf16*  resbuf = (bf16*)(ws + slab_sz + 23592960);
    bf16*  biasT  = (bf16*)(ws + slab_sz + 47185920);
    bf16*  qkvT   = (bf16*)((char*)biasT + 786432);
    bf16*  projT  = (bf16*)((char*)qkvT + 221184);
    bf16*  fc1T   = (bf16*)((char*)projT + 73728);
    bf16*  fc2T   = (bf16*)((char*)fc1T + 294912);
    bf16*  c1T    = (bf16*)((char*)fc2T + 282624);
    bf16*  c2T    = (bf16*)((char*)c1T + 221184);
    float* pooled = (float*)((char*)c2T + 221184);
    float* aab    = pooled + B_ * C_;

    hipMemsetAsync(pooled, 0, B_ * C_ * sizeof(float), stream);
    rpb_kernel<<<1536, 256, 0, stream>>>(rpb, rpi, biasT);
    twt_kernel<<<(576*192+255)/256, 256, 0, stream>>>(qkv_w, qkvT, 180, 540, 192, 576);
    twt_kernel<<<(192*192+255)/256, 256, 0, stream>>>(proj_w, projT, 180, 180, 192, 192);
    twt_kernel<<<(768*192+255)/256, 256, 0, stream>>>(fc1w, fc1T, 180, 720, 192, 768);
    twt_kernel<<<(192*736+255)/256, 256, 0, stream>>>(fc2w, fc2T, 720, 180, 736, 192);
    twc_kernel<<<(64*1728+255)/256, 256, 0, stream>>>(c1w, c1T, 180, 60, 192, 64);
    twc_kernel<<<(192*576+255)/256, 256, 0, stream>>>(c2w, c2T, 60, 180, 64, 192);

    ln_kernel<float><<<16384, 256, 0, stream>>>(x, n1g, n1b, xn);

    mgemm_kernel<1, 2, 192, 180><<<dim3(512, 1), 256, 0, stream>>>(
        xn, c1T, c1b, y1, 60, 1728, 0, 0, nullptr, nullptr, nullptr);
    mgemm_kernel<0, 2, 64, 60><<<dim3(512, 3), 256, 0, stream>>>(
        y1, c2T, c2b, resbuf, 180, 576, 0, 0, nullptr, nullptr, nullptr);
    pool_kernel<<<256, 192, 0, stream>>>(resbuf, pooled);
    ca_kernel<<<4, 192, 0, stream>>>(pooled, ca1w, ca1b, ca2w, ca2b, aab);

    for (int ch = 0; ch < CH; ch++){
        int row0 = ch * CROWS;
        mgemm_kernel<0, 1, 0, 0><<<dim3(CROWS/128, 9), 256, 0, stream>>>(
            xn, qkvT, qkv_b, qkvb, 540, 192, row0, 180, nullptr, nullptr, nullptr);
        attn_kernel<<<CWIN * NH_, 256, 0, stream>>>(qkvb, biasT, attn_o);
        mgemm_kernel<3, 0, 0, 0><<<dim3(CROWS/128, 3), 256, 0, stream>>>(
            attn_o, projT, proj_b, resbuf, 180, 192, row0, 180, x, nullptr, aab);
    }

    ln_kernel<bf16><<<16384, 256, 0, stream>>>(resbuf, n2g, n2b, xn);

    for (int ch = 0; ch < CH; ch++){
        size_t off = (size_t)ch * CROWS * C_;
        mgemm_kernel<1, 0, 0, 0><<<dim3(CROWS/128, 12), 256, 0, stream>>>(
            xn + off, fc1T, fc1b, hbuf, 720, 192, 0, 180, nullptr, nullptr, nullptr);
        mgemm_kernel<2, 0, 0, 0><<<dim3(CROWS/128, 3), 256, 0, stream>>>(
            hbuf, fc2T, fc2b, (float*)d_out + off, 180, 736, 0, 720,
            nullptr, resbuf + off, nullptr);
    }
}